// Round 4
// baseline (76.712 us; speedup 1.0000x reference)
//
#include <hip/hip_runtime.h>

#define N_SEG 256
#define HIDDEN 512
#define NWAVES 8192
#define NW_SHIFT 13
#define NEG_INF (-__builtin_inff())

// Flat decomposition: wave wv owns rows [n*wv/8192, n*(wv+1)/8192) — contiguous,
// perfectly balanced. Within its range it runs online softmax per run of equal
// segment id (batch is sorted), flushing one partial (m, d, acc[512]) per run.
// Slot for a run starting at row i: wv*rpw + (i - r0). The merge kernel can
// recompute every slot arithmetically, so no flags/atomics are needed.
__global__ __launch_bounds__(256, 8) void fused_flat(
    const float* __restrict__ x, const float* __restrict__ W,
    const int* __restrict__ batch, float* __restrict__ pm,
    float* __restrict__ pd, float* __restrict__ pacc, int n, int rpw) {
    int wv = blockIdx.x * 4 + (threadIdx.x >> 6);
    int lane = threadIdx.x & 63;
    int r0 = (int)(((long long)n * wv) >> NW_SHIFT);
    int r1 = (int)(((long long)n * (wv + 1)) >> NW_SHIFT);
    if (r0 >= r1) return;

    float4 w0 = *(const float4*)(W + lane * 8);
    float4 w1 = *(const float4*)(W + lane * 8 + 4);

    int cur = batch[r0];
    int j0 = 0;  // slot offset = start row of current run - r0
    float m = NEG_INF, d = 0.0f;
    float4 acc0 = make_float4(0, 0, 0, 0), acc1 = make_float4(0, 0, 0, 0);

    for (int i = r0; i < r1; ++i) {
        const float* xr = x + (size_t)i * HIDDEN + lane * 8;
        float4 a0 = *(const float4*)xr;
        float4 a1 = *(const float4*)(xr + 4);
        int sg = batch[i];            // same for all lanes (broadcast, L1-hot)
        if (sg != cur) {              // wave-uniform, ~2x per wave
            int slot = wv * rpw + j0;
            if (lane == 0) { pm[slot] = m; pd[slot] = d; }
            float* dst = pacc + (size_t)slot * HIDDEN + lane * 8;
            *(float4*)dst = acc0; *(float4*)(dst + 4) = acc1;
            m = NEG_INF; d = 0.0f;
            acc0 = make_float4(0, 0, 0, 0); acc1 = make_float4(0, 0, 0, 0);
            cur = sg; j0 = i - r0;
        }
        // gate = dot(row, W) (bias cancels in softmax)
        float g = a0.x * w0.x + a0.y * w0.y + a0.z * w0.z + a0.w * w0.w
                + a1.x * w1.x + a1.y * w1.y + a1.z * w1.z + a1.w * w1.w;
        #pragma unroll
        for (int off = 32; off; off >>= 1) g += __shfl_xor(g, off, 64);
        float mn = fmaxf(m, g);
        float sc = __expf(m - mn);    // 0 on first row of run, 1 if max unchanged
        float p  = __expf(g - mn);
        d = d * sc + p;
        acc0.x = acc0.x * sc + p * a0.x;  acc0.y = acc0.y * sc + p * a0.y;
        acc0.z = acc0.z * sc + p * a0.z;  acc0.w = acc0.w * sc + p * a0.w;
        acc1.x = acc1.x * sc + p * a1.x;  acc1.y = acc1.y * sc + p * a1.y;
        acc1.z = acc1.z * sc + p * a1.z;  acc1.w = acc1.w * sc + p * a1.w;
        m = mn;
    }
    int slot = wv * rpw + j0;         // final run flush
    if (lane == 0) { pm[slot] = m; pd[slot] = d; }
    float* dst = pacc + (size_t)slot * HIDDEN + lane * 8;
    *(float4*)dst = acc0; *(float4*)(dst + 4) = acc1;
}

__device__ __forceinline__ int wave_of(int r, int n) {
    int wv = (int)(((long long)r << NW_SHIFT) / n);
    while ((int)(((long long)n * (wv + 1)) >> NW_SHIFT) <= r) ++wv;
    while ((int)(((long long)n * wv) >> NW_SHIFT) > r) --wv;
    return wv;
}

// One block per (segment, half-row): binary-search segment bounds, locate all
// contributing wave partials arithmetically, softmax-merge, write 256 columns.
__global__ __launch_bounds__(256) void merge_flat(
    const int* __restrict__ batch, const float* __restrict__ pm,
    const float* __restrict__ pd, const float* __restrict__ pacc,
    float* __restrict__ out, int n, int rpw) {
    int s = blockIdx.x >> 1;
    int col = ((blockIdx.x & 1) << 8) + threadIdx.x;

    int lo = 0, hi = n;
    while (lo < hi) { int mid = (lo + hi) >> 1; if (batch[mid] < s) lo = mid + 1; else hi = mid; }
    int ss = lo; hi = n;
    while (lo < hi) { int mid = (lo + hi) >> 1; if (batch[mid] < s + 1) lo = mid + 1; else hi = mid; }
    int se = lo;
    if (ss >= se) { out[s * HIDDEN + col] = 0.0f; return; }  // empty segment

    int wlo = wave_of(ss, n), whi = wave_of(se - 1, n);

    float M = NEG_INF;
    for (int wv = wlo; wv <= whi; ++wv) {
        int wr0 = (int)(((long long)n * wv) >> NW_SHIFT);
        int wr1 = (int)(((long long)n * (wv + 1)) >> NW_SHIFT);
        if (wr0 >= wr1) continue;
        int st = ss > wr0 ? ss : wr0;
        M = fmaxf(M, pm[wv * rpw + (st - wr0)]);
    }
    float D = 0.0f;
    for (int wv = wlo; wv <= whi; ++wv) {
        int wr0 = (int)(((long long)n * wv) >> NW_SHIFT);
        int wr1 = (int)(((long long)n * (wv + 1)) >> NW_SHIFT);
        if (wr0 >= wr1) continue;
        int st = ss > wr0 ? ss : wr0;
        int slot = wv * rpw + (st - wr0);
        D += pd[slot] * __expf(pm[slot] - M);
    }
    float invD = 1.0f / (D + 1e-16f);
    float num = 0.0f;
    for (int wv = wlo; wv <= whi; ++wv) {
        int wr0 = (int)(((long long)n * wv) >> NW_SHIFT);
        int wr1 = (int)(((long long)n * (wv + 1)) >> NW_SHIFT);
        if (wr0 >= wr1) continue;
        int st = ss > wr0 ? ss : wr0;
        int slot = wv * rpw + (st - wr0);
        num += pacc[(size_t)slot * HIDDEN + col] * __expf(pm[slot] - M);
    }
    out[s * HIDDEN + col] = num * invD;
}

extern "C" void kernel_launch(void* const* d_in, const int* in_sizes, int n_in,
                              void* d_out, int out_size, void* d_ws, size_t ws_size,
                              hipStream_t stream) {
    const float* x     = (const float*)d_in[0];
    const int*   batch = (const int*)d_in[1];
    const float* W     = (const float*)d_in[2];
    int n = in_sizes[1];
    float* out = (float*)d_out;

    int rpw = (n + NWAVES - 1) >> NW_SHIFT;  // max rows (=slots) per wave
    // ws: pm[NWAVES*rpw] | pd[NWAVES*rpw] | pacc[NWAVES*rpw*512]  (~219 MB)
    float* pm   = (float*)d_ws;
    float* pd   = pm + (size_t)NWAVES * rpw;
    float* pacc = pd + (size_t)NWAVES * rpw;

    fused_flat<<<NWAVES / 4, 256, 0, stream>>>(x, W, batch, pm, pd, pacc, n, rpw);
    merge_flat<<<N_SEG * 2, 256, 0, stream>>>(batch, pm, pd, pacc, out, n, rpw);
}